// Round 9
// baseline (327.521 us; speedup 1.0000x reference)
//
#include <hip/hip_runtime.h>
#include <hip/hip_fp16.h>
#include <stdint.h>

#define IN_F   4096
#define OUT_F  11008
#define TOKENS 2048
#define BM 128
#define BN 128
#define BK 32
#define NT (IN_F / BK)     // 128 K-tiles
#define NGROUP 32
#define OPW (OUT_F / 8)

typedef _Float16 f16;
typedef __attribute__((ext_vector_type(2))) _Float16 f16x2;
typedef __attribute__((ext_vector_type(8))) _Float16 f16x8;
typedef __attribute__((ext_vector_type(4))) float f32x4;

typedef __attribute__((address_space(3))) uint32_t lds_u32_t;
typedef const __attribute__((address_space(1))) uint32_t glb_u32_t;

#define SB0() __builtin_amdgcn_sched_barrier(0)

static __device__ __forceinline__ void gload_lds16(const void* g, void* l) {
    __builtin_amdgcn_global_load_lds((glb_u32_t*)g, (lds_u32_t*)l, 16, 0, 0);
}

// dequant one packed word -> 8 f16 in pair-permuted k-order (j, j+4)
static __device__ __forceinline__ f16x8 dequant8(uint32_t w, f16x2 sv, f16x2 zv) {
    uint32_t p0 = (w & 0x000F000Fu) | 0x64006400u;           // 1024 + nibble (exact f16)
    uint32_t p1 = ((w >> 4)  & 0x000F000Fu) | 0x64006400u;
    uint32_t p2 = ((w >> 8)  & 0x000F000Fu) | 0x64006400u;
    uint32_t p3 = ((w >> 12) & 0x000F000Fu) | 0x64006400u;
    f16x2 h0 = (__builtin_bit_cast(f16x2, p0) + zv) * sv;    // exact (w - z - 1), then * s
    f16x2 h1 = (__builtin_bit_cast(f16x2, p1) + zv) * sv;
    f16x2 h2 = (__builtin_bit_cast(f16x2, p2) + zv) * sv;
    f16x2 h3 = (__builtin_bit_cast(f16x2, p3) + zv) * sv;
    f16x8 o;
    o[0] = h0[0]; o[1] = h0[1];
    o[2] = h1[0]; o[3] = h1[1];
    o[4] = h2[0]; o[5] = h2[1];
    o[6] = h3[0]; o[7] = h3[1];
    return o;
}

// pre-pass: x f32 -> f16 with intra-octet pair permutation (0,4,1,5,2,6,3,7)
__global__ __launch_bounds__(256) void cvt_perm_kernel(const float* __restrict__ x,
                                                       f16* __restrict__ xws) {
    const int o = blockIdx.x * 256 + threadIdx.x;   // octet id
    const float4 a = *reinterpret_cast<const float4*>(x + (size_t)o * 8);
    const float4 b = *reinterpret_cast<const float4*>(x + (size_t)o * 8 + 4);
    f16x8 v;
    v[0] = (f16)a.x; v[1] = (f16)b.x; v[2] = (f16)a.y; v[3] = (f16)b.y;
    v[4] = (f16)a.z; v[5] = (f16)b.z; v[6] = (f16)a.w; v[7] = (f16)b.w;
    *reinterpret_cast<f16x8*>(xws + (size_t)o * 8) = v;
}

// Sub-tile body: compute buf C (tile T), stage tile T+1 into buf C^1.
// LOADSC: prefetch next group's scale/zero words (issued before the A-gloads).
// DOMKC:  rebuild sv/zv from prefetched words BEFORE this body's stage_B.
#define SUBTILE(C, T, LOADSC, DOMKC, WCUR, WNXT)                                  \
  {                                                                               \
    const int tn1_ = ((T) + 1 < NT) ? (T) + 1 : NT - 1;                           \
    const int tn2_ = ((T) + 2 < NT) ? (T) + 2 : NT - 1;                           \
    if (LOADSC) {                                                                 \
      const int g1_ = ((T) >> 2) + 1 < NGROUP ? ((T) >> 2) + 1 : NGROUP - 1;      \
      swN = qscales[(size_t)g1_ * OUT_F + ncol];                                  \
      zwN = qzeros[(size_t)g1_ * OPW + (ncol >> 3)];                              \
    }                                                                             \
    if (DOMKC) { mkc(sv, zv, swN, zwN); }                                         \
    stage_B((C) ^ 1, WCUR, sv, zv);                                               \
    if constexpr (USE_WS) stage_A_g((C) ^ 1, tn1_); else stage_A_f((C) ^ 1, tn1_);\
    SB0();                                                                        \
    load_bw(tn2_, WNXT);                                                          \
    SB0();                                                                        \
    compute(C);                                                                   \
    if constexpr (USE_WS)                                                         \
      asm volatile("s_waitcnt vmcnt(2)" ::: "memory");  /* A(T+1) landed */       \
    asm volatile("s_waitcnt lgkmcnt(0)" ::: "memory");                            \
    __builtin_amdgcn_s_barrier();                                                 \
  }

template<bool USE_WS>
__global__ __launch_bounds__(256, 4) void qgemm_kernel(
    const float*    __restrict__ x,
    const f16*      __restrict__ xws,
    const uint32_t* __restrict__ qweight,
    const uint32_t* __restrict__ qzeros,
    const int*      __restrict__ qscales,
    const float*    __restrict__ qscales_zeros,
    const float*    __restrict__ qscales_scales,
    float*          __restrict__ out)
{
    // chunk (row, slot∈[0,4)) holds k-octet slot ^ ((row>>1)&3):
    // 8 consecutive rows x 4 slots cover all 32 banks -> conflict-free b128 phases
    __shared__ __align__(16) f16 Abuf[2][BM * BK];   // 2 x 8 KiB
    __shared__ __align__(16) f16 Bbuf[2][BN * BK];   // 2 x 8 KiB  (32 KiB -> 4 blocks/CU)

    const int tid  = threadIdx.x;
    const int lane = tid & 63;
    const int wid  = tid >> 6;      // 0..3
    const int wm   = wid >> 1;      // 0..1 (M half: 64 rows)
    const int wn   = wid & 1;       // 0..1 (N half: 64 cols)

    // XCD map: bid&7 = XCD; mt = bid&15 -> XCD x hosts A-panels {x, x+8} in its L2
    const int mt = blockIdx.x & 15;
    const int nt = blockIdx.x >> 4;
    const int m0 = mt * BM;
    const int n0 = nt * BN;

    // ---------- B side: thread owns 1 column, 2 consecutive k-octet rows ----------
    const int colb = tid & 127;
    const int og2  = (tid >> 7) << 1;    // 0 or 2
    const int ncol = n0 + colb;
    const float ssv   = qscales_scales[ncol];
    const float qzssv = qscales_zeros[ncol] * ssv;
    int bo[2];
    #pragma unroll
    for (int r = 0; r < 2; ++r)
        bo[r] = colb * BK + ((og2 + r) ^ ((colb >> 1) & 3)) * 8;
    const uint32_t* bptr = qweight + (size_t)og2 * OUT_F + ncol;

    // ---------- A side: 2 chunks/thread, linear LDS dest, swizzled source ----------
    const f16*   asrc[2];
    const float* fsrc[2];
    int aoff[2];
    #pragma unroll
    for (int i = 0; i < 2; ++i) {
        const int cid = i * 256 + tid;           // 0..511 chunks
        const int row = cid >> 2, slot = cid & 3;
        const int oct = slot ^ ((row >> 1) & 3);
        asrc[i] = xws + (size_t)(m0 + row) * IN_F + oct * 8;
        fsrc[i] = x   + (size_t)(m0 + row) * IN_F + oct * 8;
        aoff[i] = cid * 8;                       // f16 elems (16B chunks)
    }

    // ---------- fragment read offsets ----------
    const int lr = lane & 15;
    const int lo = lane >> 4;            // k-octet 0..3
    int offA[4], offB[4];
    #pragma unroll
    for (int f = 0; f < 4; ++f) {
        const int ra = wm * 64 + f * 16 + lr;
        offA[f] = ra * BK + (lo ^ ((ra >> 1) & 3)) * 8;
        const int rb = wn * 64 + f * 16 + lr;
        offB[f] = rb * BK + (lo ^ ((rb >> 1) & 3)) * 8;
    }

    f32x4 acc[4][4];
    #pragma unroll
    for (int i = 0; i < 4; ++i)
        #pragma unroll
        for (int j = 0; j < 4; ++j) {
            f32x4 z = {0.f, 0.f, 0.f, 0.f};
            acc[i][j] = z;
        }

    auto load_bw = [&](int t_, uint32_t* w) {
        const uint32_t* p = bptr + (size_t)t_ * 4 * OUT_F;
        w[0] = p[0];
        w[1] = p[OUT_F];
    };
    auto mkc = [&](f16x2& sv_, f16x2& zv_, int sw_, uint32_t zw_) {
        const float sf = (float)sw_ * ssv - qzssv;
        const int   z  = (int)((zw_ >> ((ncol & 7) * 4)) & 0xFu);
        const f16 sh = (f16)sf;
        const f16 zh = (f16)(float)(-(1025 + z));   // -(1024 + (z+1)), exact in f16
        sv_[0] = sh; sv_[1] = sh;
        zv_[0] = zh; zv_[1] = zh;
    };
    auto stage_B = [&](int buf, const uint32_t* w, f16x2 sv_, f16x2 zv_) {
        #pragma unroll
        for (int r = 0; r < 2; ++r)
            *reinterpret_cast<f16x8*>(&Bbuf[buf][bo[r]]) = dequant8(w[r], sv_, zv_);
    };
    auto stage_A_g = [&](int buf, int t_) {
        #pragma unroll
        for (int i = 0; i < 2; ++i)
            gload_lds16(asrc[i] + (size_t)t_ * BK, &Abuf[buf][aoff[i]]);
    };
    auto stage_A_f = [&](int buf, int t_) {
        #pragma unroll
        for (int i = 0; i < 2; ++i) {
            const float* p = fsrc[i] + (size_t)t_ * BK;
            const float4 v0 = *reinterpret_cast<const float4*>(p);
            const float4 v1 = *reinterpret_cast<const float4*>(p + 4);
            f16x8 v;
            v[0] = (f16)v0.x; v[1] = (f16)v1.x; v[2] = (f16)v0.y; v[3] = (f16)v1.y;
            v[4] = (f16)v0.z; v[5] = (f16)v1.z; v[6] = (f16)v0.w; v[7] = (f16)v1.w;
            *reinterpret_cast<f16x8*>(&Abuf[buf][aoff[i]]) = v;
        }
    };
    auto compute = [&](int buf) {
        f16x8 af[4], bf[4];
        #pragma unroll
        for (int f = 0; f < 4; ++f)
            af[f] = *reinterpret_cast<const f16x8*>(&Abuf[buf][offA[f]]);
        #pragma unroll
        for (int f = 0; f < 4; ++f)
            bf[f] = *reinterpret_cast<const f16x8*>(&Bbuf[buf][offB[f]]);
        __builtin_amdgcn_s_setprio(1);
        #pragma unroll
        for (int i = 0; i < 4; ++i)
            #pragma unroll
            for (int j = 0; j < 4; ++j)
                acc[i][j] = __builtin_amdgcn_mfma_f32_16x16x32_f16(
                    af[i], bf[j], acc[i][j], 0, 0, 0);
        __builtin_amdgcn_s_setprio(0);
    };

    uint32_t wa[2], wb[2];
    int swN; uint32_t zwN;
    f16x2 sv, zv;

    // ---------------- prologue: stage tile 0; prime words(1) ----------------
    {
        uint32_t w00[2];
        load_bw(0, w00);
        load_bw(1, wa);
        const int      sw0 = qscales[ncol];
        const uint32_t zw0 = qzeros[ncol >> 3];
        if constexpr (USE_WS) stage_A_g(0, 0); else stage_A_f(0, 0);
        mkc(sv, zv, sw0, zw0);                 // group 0 (tiles 0..3)
        stage_B(0, w00, sv, zv);
        asm volatile("s_waitcnt vmcnt(0)" ::: "memory");
        asm volatile("s_waitcnt lgkmcnt(0)" ::: "memory");
        __builtin_amdgcn_s_barrier();
    }

    // ---------------- main loop: 4 tiles (1 group) per iteration ----------------
    for (int i = 0; i < NT / 4; ++i) {
        const int t0 = i * 4;
        SUBTILE(0, t0,     false, false, wa, wb)   // stage tile t0+1 (group i)
        SUBTILE(1, t0 + 1, true,  false, wb, wa)   // + load scales group i+1
        SUBTILE(0, t0 + 2, false, false, wa, wb)
        SUBTILE(1, t0 + 3, false, true,  wb, wa)   // mkc group i+1; stage tile t0+4
    }

    // ---------------- epilogue: C/D layout col=lane&15, row=(lane>>4)*4+reg ----------
    const int orow = m0 + wm * 64 + lo * 4;
    const int ocol = n0 + wn * 64 + lr;
    #pragma unroll
    for (int i = 0; i < 4; ++i)
        #pragma unroll
        for (int j = 0; j < 4; ++j) {
            #pragma unroll
            for (int r = 0; r < 4; ++r)
                out[(size_t)(orow + i * 16 + r) * OUT_F + ocol + j * 16] = acc[i][j][r];
        }
}

extern "C" void kernel_launch(void* const* d_in, const int* in_sizes, int n_in,
                              void* d_out, int out_size, void* d_ws, size_t ws_size,
                              hipStream_t stream) {
    const float*    xp  = (const float*)d_in[0];
    const uint32_t* qw  = (const uint32_t*)d_in[1];
    const uint32_t* qz  = (const uint32_t*)d_in[2];
    const int*      qs  = (const int*)d_in[3];
    const float*    qsz = (const float*)d_in[4];
    const float*    qss = (const float*)d_in[5];
    // d_in[6] = g_idx: identity grouping (k/128), folded into the kernel.
    float* outp = (float*)d_out;

    const int grid = (TOKENS / BM) * (OUT_F / BN);   // 16 * 86 = 1376
    const size_t need = (size_t)TOKENS * IN_F * sizeof(f16);   // 16 MiB

    if (ws_size >= need) {
        f16* xws = (f16*)d_ws;
        cvt_perm_kernel<<<(TOKENS * IN_F / 8) / 256, 256, 0, stream>>>(xp, xws);
        qgemm_kernel<true><<<grid, 256, 0, stream>>>(xp, xws, qw, qz, qs, qsz, qss, outp);
    } else {
        qgemm_kernel<false><<<grid, 256, 0, stream>>>(xp, (const f16*)nullptr,
                                                      qw, qz, qs, qsz, qss, outp);
    }
}

// Round 10
// 220.805 us; speedup vs baseline: 1.4833x; 1.4833x over previous
//
#include <hip/hip_runtime.h>
#include <hip/hip_fp16.h>
#include <stdint.h>

#define IN_F   4096
#define OUT_F  11008
#define TOKENS 2048
#define BM 128
#define BN 128
#define BK 64
#define NT (IN_F / BK)     // 64 K-tiles
#define NGROUP 32
#define OPW (OUT_F / 8)

typedef _Float16 f16;
typedef __attribute__((ext_vector_type(2))) _Float16 f16x2;
typedef __attribute__((ext_vector_type(8))) _Float16 f16x8;
typedef __attribute__((ext_vector_type(4))) float f32x4;

typedef __attribute__((address_space(3))) uint32_t lds_u32_t;
typedef const __attribute__((address_space(1))) uint32_t glb_u32_t;

#define SB0() __builtin_amdgcn_sched_barrier(0)

static __device__ __forceinline__ void gload_lds16(const void* g, void* l) {
    __builtin_amdgcn_global_load_lds((glb_u32_t*)g, (lds_u32_t*)l, 16, 0, 0);
}

// dequant one packed word -> 8 f16 in pair-permuted k-order (j, j+4)
static __device__ __forceinline__ f16x8 dequant8(uint32_t w, f16x2 sv, f16x2 zv) {
    uint32_t p0 = (w & 0x000F000Fu) | 0x64006400u;           // 1024 + nibble (exact f16)
    uint32_t p1 = ((w >> 4)  & 0x000F000Fu) | 0x64006400u;
    uint32_t p2 = ((w >> 8)  & 0x000F000Fu) | 0x64006400u;
    uint32_t p3 = ((w >> 12) & 0x000F000Fu) | 0x64006400u;
    f16x2 h0 = (__builtin_bit_cast(f16x2, p0) + zv) * sv;    // exact (w - z - 1), then * s
    f16x2 h1 = (__builtin_bit_cast(f16x2, p1) + zv) * sv;
    f16x2 h2 = (__builtin_bit_cast(f16x2, p2) + zv) * sv;
    f16x2 h3 = (__builtin_bit_cast(f16x2, p3) + zv) * sv;
    f16x8 o;
    o[0] = h0[0]; o[1] = h0[1];
    o[2] = h1[0]; o[3] = h1[1];
    o[4] = h2[0]; o[5] = h2[1];
    o[6] = h3[0]; o[7] = h3[1];
    return o;
}

// pre-pass: x f32 -> f16 with intra-octet pair permutation (0,4,1,5,2,6,3,7)
__global__ __launch_bounds__(256) void cvt_perm_kernel(const float* __restrict__ x,
                                                       f16* __restrict__ xws) {
    const int o = blockIdx.x * 256 + threadIdx.x;   // octet id
    const float4 a = *reinterpret_cast<const float4*>(x + (size_t)o * 8);
    const float4 b = *reinterpret_cast<const float4*>(x + (size_t)o * 8 + 4);
    f16x8 v;
    v[0] = (f16)a.x; v[1] = (f16)b.x; v[2] = (f16)a.y; v[3] = (f16)b.y;
    v[4] = (f16)a.z; v[5] = (f16)b.z; v[6] = (f16)a.w; v[7] = (f16)b.w;
    *reinterpret_cast<f16x8*>(xws + (size_t)o * 8) = v;
}

template<bool USE_WS>
__global__ __launch_bounds__(512, 4) void qgemm_kernel(
    const float*    __restrict__ x,
    const f16*      __restrict__ xws,
    const uint32_t* __restrict__ qweight,
    const uint32_t* __restrict__ qzeros,
    const int*      __restrict__ qscales,
    const float*    __restrict__ qscales_zeros,
    const float*    __restrict__ qscales_scales,
    float*          __restrict__ out)
{
    // One 64 KiB heap: per buffer, A tile then B tile. Chunk (row, slot) holds
    // k-octet slot ^ (row&7) — conflict-free for every aligned 8-lane b128 phase.
    // Epilogue reuses the whole heap as the cross-k-group reduction scratch.
    __shared__ __align__(16) f16 heap[2][(BM + BN) * BK];    // 64 KiB -> 2 blocks/CU

    f16* const Ab0 = &heap[0][0];
    f16* const Ab1 = &heap[1][0];
    f16* const Bb0 = &heap[0][BM * BK];
    f16* const Bb1 = &heap[1][BM * BK];

    const int tid  = threadIdx.x;
    const int lane = tid & 63;
    const int wid  = tid >> 6;      // 0..7
    const int kg   = wid >> 2;      // 0..1 : k-octet group (0-3 | 4-7)
    const int wm   = (wid >> 1) & 1;
    const int wn   = wid & 1;

    // XCD map: bid&7 = XCD; mt = bid&15 -> XCD x hosts A-panels {x, x+8} in its L2
    const int mt = blockIdx.x & 15;
    const int nt = blockIdx.x >> 4;
    const int m0 = mt * BM;
    const int n0 = nt * BN;

    // ---------- B side: thread owns 1 column, 2 consecutive k-octet rows ----------
    const int colb = tid & 127;
    const int og2  = (tid >> 7) << 1;    // 0,2,4,6
    const int ncol = n0 + colb;
    const float ssv   = qscales_scales[ncol];
    const float qzssv = qscales_zeros[ncol] * ssv;
    int bo[2];
    #pragma unroll
    for (int r = 0; r < 2; ++r)
        bo[r] = colb * BK + ((og2 + r) ^ (colb & 7)) * 8;
    const uint32_t* bptr = qweight + (size_t)og2 * OUT_F + ncol;

    // ---------- A side: 2 chunks/thread (rows r, r+64 share the same swizzle) ----
    const int arow = tid >> 3;                 // 0..63
    const int aslot = tid & 7;
    const int aoct = aslot ^ (arow & 7);       // (row+64)&7 == row&7 -> same oct
    const f16*   asrc0 = xws + (size_t)(m0 + arow) * IN_F + aoct * 8;
    const float* fsrc0 = x   + (size_t)(m0 + arow) * IN_F + aoct * 8;
    const int aoff0 = tid * 8;                 // chunk cid = tid
    const int aoff1 = (tid + 512) * 8;         // chunk cid = tid + 512

    // ---------- fragment read offsets (this wave's k-step only) ----------
    const int lr = lane & 15;
    const int lo = lane >> 4;
    const int koct = kg * 4 + lo;              // 0..7
    int offA[4], offB[4];
    #pragma unroll
    for (int f = 0; f < 4; ++f) {
        const int ra = wm * 64 + f * 16 + lr;
        offA[f] = ra * BK + (koct ^ (ra & 7)) * 8;
        const int rb = wn * 64 + f * 16 + lr;
        offB[f] = rb * BK + (koct ^ (rb & 7)) * 8;
    }

    f32x4 acc[4][4];
    #pragma unroll
    for (int i = 0; i < 4; ++i)
        #pragma unroll
        for (int j = 0; j < 4; ++j) {
            f32x4 z = {0.f, 0.f, 0.f, 0.f};
            acc[i][j] = z;
        }

    auto load_bw = [&](int t_, uint32_t* w) {
        const uint32_t* p = bptr + (size_t)t_ * 8 * OUT_F;
        w[0] = p[0];
        w[1] = p[OUT_F];
    };
    auto mkc = [&](f16x2& sv_, f16x2& zv_, int sw_, uint32_t zw_) {
        const float sf = (float)sw_ * ssv - qzssv;
        const int   z  = (int)((zw_ >> ((ncol & 7) * 4)) & 0xFu);
        const f16 sh = (f16)sf;
        const f16 zh = (f16)(float)(-(1025 + z));   // -(1024 + (z+1)), exact in f16
        sv_[0] = sh; sv_[1] = sh;
        zv_[0] = zh; zv_[1] = zh;
    };
    auto stage_B = [&](f16* Bb, const uint32_t* w, f16x2 sv_, f16x2 zv_) {
        *reinterpret_cast<f16x8*>(&Bb[bo[0]]) = dequant8(w[0], sv_, zv_);
        *reinterpret_cast<f16x8*>(&Bb[bo[1]]) = dequant8(w[1], sv_, zv_);
    };
    auto stage_A_g = [&](f16* Ab, int t_) {
        gload_lds16(asrc0 + (size_t)t_ * BK, &Ab[aoff0]);
        gload_lds16(asrc0 + (size_t)t_ * BK + (size_t)64 * IN_F, &Ab[aoff1]);
    };
    auto stage_A_f = [&](f16* Ab, int t_) {
        #pragma unroll
        for (int i = 0; i < 2; ++i) {
            const float* p = fsrc0 + (size_t)t_ * BK + (size_t)(64 * i) * IN_F;
            const float4 v0 = *reinterpret_cast<const float4*>(p);
            const float4 v1 = *reinterpret_cast<const float4*>(p + 4);
            f16x8 v;
            v[0] = (f16)v0.x; v[1] = (f16)v1.x; v[2] = (f16)v0.y; v[3] = (f16)v1.y;
            v[4] = (f16)v0.z; v[5] = (f16)v1.z; v[6] = (f16)v0.w; v[7] = (f16)v1.w;
            *reinterpret_cast<f16x8*>(&Ab[i == 0 ? aoff0 : aoff1]) = v;
        }
    };
    auto compute = [&](const f16* Ab, const f16* Bb) {
        f16x8 af[4], bf[4];
        #pragma unroll
        for (int f = 0; f < 4; ++f)
            af[f] = *reinterpret_cast<const f16x8*>(&Ab[offA[f]]);
        #pragma unroll
        for (int f = 0; f < 4; ++f)
            bf[f] = *reinterpret_cast<const f16x8*>(&Bb[offB[f]]);
        __builtin_amdgcn_s_setprio(1);
        #pragma unroll
        for (int i = 0; i < 4; ++i)
            #pragma unroll
            for (int j = 0; j < 4; ++j)
                acc[i][j] = __builtin_amdgcn_mfma_f32_16x16x32_f16(
                    af[i], bf[j], acc[i][j], 0, 0, 0);
        __builtin_amdgcn_s_setprio(0);
    };

    uint32_t wcur[2], wnxt[2];
    int swN; uint32_t zwN;
    f16x2 sv, zv, svN, zvN;

    // ---------------- prologue: stage tile 0; prime tile-1 words + group-1 scales ----
    {
        uint32_t w0[2];
        load_bw(0, w0);
        const int      sw0 = qscales[ncol];
        const uint32_t zw0 = qzeros[ncol >> 3];
        if constexpr (USE_WS) stage_A_g(Ab0, 0); else stage_A_f(Ab0, 0);
        load_bw(1, wcur);
        swN = qscales[OUT_F + ncol];           // group 1
        zwN = qzeros[OPW + (ncol >> 3)];
        mkc(sv, zv, sw0, zw0);                 // group 0 (tiles 0,1)
        stage_B(Bb0, w0, sv, zv);
        asm volatile("s_waitcnt vmcnt(0)" ::: "memory");
        asm volatile("s_waitcnt lgkmcnt(0)" ::: "memory");
        __builtin_amdgcn_s_barrier();
    }

    // ---------------- main loop: 2 tiles per iteration, 1 barrier per tile ----------
    for (int t = 0; t < NT; t += 2) {
        // ---- even body: compute tile t (buf0); stage tile t+1 (buf1)
        {
            mkc(svN, zvN, swN, zwN);                   // group t/2+1 (for odd body)
            stage_B(Bb1, wcur, sv, zv);                // tile t+1, group t/2
            if constexpr (USE_WS) stage_A_g(Ab1, t + 1); else stage_A_f(Ab1, t + 1);
            SB0();
            load_bw(t + 2 < NT ? t + 2 : NT - 1, wnxt);
            {
                const int g2 = (t >> 1) + 2 < NGROUP ? (t >> 1) + 2 : NGROUP - 1;
                swN = qscales[(size_t)g2 * OUT_F + ncol];
                zwN = qzeros[(size_t)g2 * OPW + (ncol >> 3)];
            }
            SB0();
            compute(Ab0, Bb0);
            if constexpr (USE_WS)
                asm volatile("s_waitcnt vmcnt(4)" ::: "memory");  // A(t+1) landed
            asm volatile("s_waitcnt lgkmcnt(0)" ::: "memory");
            __builtin_amdgcn_s_barrier();
        }
        // ---- odd body: compute tile t+1 (buf1); stage tile t+2 (buf0)
        {
            sv = svN; zv = zvN;                        // group t/2+1
            stage_B(Bb0, wnxt, sv, zv);                // tile t+2
            const int tn2 = t + 2 < NT ? t + 2 : NT - 1;
            if constexpr (USE_WS) stage_A_g(Ab0, tn2); else stage_A_f(Ab0, tn2);
            SB0();
            load_bw(t + 3 < NT ? t + 3 : NT - 1, wcur);
            SB0();
            compute(Ab1, Bb1);
            if constexpr (USE_WS)
                asm volatile("s_waitcnt vmcnt(2)" ::: "memory");  // A(t+2) landed
            asm volatile("s_waitcnt lgkmcnt(0)" ::: "memory");
            __builtin_amdgcn_s_barrier();
        }
    }

    // ---------------- cross-k-group reduction + epilogue ----------------
    __syncthreads();                                   // all LDS reads done
    f32x4* scratch = reinterpret_cast<f32x4*>(&heap[0][0]);   // 64 KiB = 4096 f32x4
    if (kg == 1) {
        const int base = (wid - 4) * 1024;             // 16 KiB per wave
        #pragma unroll
        for (int i = 0; i < 4; ++i)
            #pragma unroll
            for (int j = 0; j < 4; ++j)
                scratch[base + (i * 4 + j) * 64 + lane] = acc[i][j];
    }
    __syncthreads();
    if (kg == 0) {
        const int base = wid * 1024;
        #pragma unroll
        for (int i = 0; i < 4; ++i)
            #pragma unroll
            for (int j = 0; j < 4; ++j) {
                const f32x4 p = scratch[base + (i * 4 + j) * 64 + lane];
                acc[i][j].x += p.x; acc[i][j].y += p.y;
                acc[i][j].z += p.z; acc[i][j].w += p.w;
            }
        // C/D layout: col = lane&15, row = (lane>>4)*4 + reg
        const int orow = m0 + wm * 64 + lo * 4;
        const int ocol = n0 + wn * 64 + lr;
        #pragma unroll
        for (int i = 0; i < 4; ++i)
            #pragma unroll
            for (int j = 0; j < 4; ++j) {
                #pragma unroll
                for (int r = 0; r < 4; ++r)
                    out[(size_t)(orow + i * 16 + r) * OUT_F + ocol + j * 16] = acc[i][j][r];
            }
    }
}

extern "C" void kernel_launch(void* const* d_in, const int* in_sizes, int n_in,
                              void* d_out, int out_size, void* d_ws, size_t ws_size,
                              hipStream_t stream) {
    const float*    xp  = (const float*)d_in[0];
    const uint32_t* qw  = (const uint32_t*)d_in[1];
    const uint32_t* qz  = (const uint32_t*)d_in[2];
    const int*      qs  = (const int*)d_in[3];
    const float*    qsz = (const float*)d_in[4];
    const float*    qss = (const float*)d_in[5];
    // d_in[6] = g_idx: identity grouping (k/128), folded into the kernel.
    float* outp = (float*)d_out;

    const int grid = (TOKENS / BM) * (OUT_F / BN);   // 16 * 86 = 1376
    const size_t need = (size_t)TOKENS * IN_F * sizeof(f16);   // 16 MiB

    if (ws_size >= need) {
        f16* xws = (f16*)d_ws;
        cvt_perm_kernel<<<(TOKENS * IN_F / 8) / 256, 256, 0, stream>>>(xp, xws);
        qgemm_kernel<true><<<grid, 512, 0, stream>>>(xp, xws, qw, qz, qs, qsz, qss, outp);
    } else {
        qgemm_kernel<false><<<grid, 512, 0, stream>>>(xp, (const f16*)nullptr,
                                                      qw, qz, qs, qsz, qss, outp);
    }
}